// Round 3
// baseline (5314.367 us; speedup 1.0000x reference)
//
#include <hip/hip_runtime.h>
#include <cstdint>
#include <cstddef>

// ---------------------------------------------------------------------------
// JIIF fused pipeline (round 9):
//   - gemm_f16_256 made PERSISTENT: grid = Rc/256 blocks (1/CU); each block
//     keeps its 256-row m-block and cycles the nt n-tiles (L0:4, L1:2, L2:1)
//     as one continuous K-tile stream.  Stage targets index the global
//     K-tile counter g = t*nk+kt, so prefetch runs ACROSS tile boundaries:
//     ramp/drain happen once per block instead of nt times, and the
//     (register-only) epilogue overlaps the next tile's in-flight DMA.
//     nk even for all layers -> buffer parity cur=kt&1 is continuous.
//   - otherwise round-8 schedule: 8 waves, BK=64 as 2 K-half buffers,
//     counted vmcnt(6), raw barriers + lgkmcnt(0), setprio around MFMA,
//     XOR chunk swizzle (0 bank conflicts), c=16 L3-resident chunking.
// Rows ordered point-major: row = point*4 + shift.
// ---------------------------------------------------------------------------

typedef unsigned short u16;
typedef unsigned int u32;
typedef _Float16 half8 __attribute__((ext_vector_type(8)));
typedef float floatx4 __attribute__((ext_vector_type(4)));
typedef float floatx2 __attribute__((ext_vector_type(2)));
typedef u32 u32x2 __attribute__((ext_vector_type(2)));
typedef u32 u32x4 __attribute__((ext_vector_type(4)));

__device__ __forceinline__ u16 f2h(float x) {
    _Float16 h = (_Float16)x;
    return __builtin_bit_cast(unsigned short, h);
}
__device__ __forceinline__ float h2f(u16 u) {
    return (float)__builtin_bit_cast(_Float16, u);
}

// async 16B global -> LDS (wave-uniform LDS base + lane*16)
__device__ __forceinline__ void cp_async16(const void* gsrc, void* lds) {
#if defined(__has_builtin) && __has_builtin(__builtin_amdgcn_global_load_lds)
    __builtin_amdgcn_global_load_lds(
        (__attribute__((address_space(1))) void*)(uintptr_t)gsrc,
        (__attribute__((address_space(3))) void*)(uint32_t)(uintptr_t)lds,
        16, 0, 0);
#else
    *(u32x4*)lds = *(const u32x4*)gsrc;
#endif
}

// ---------------- transpose [B][C=128][HW] fp32 -> [B][HW][C] fp16 ----------
__global__ void transpose_chw_hwc(const float* __restrict__ src,
                                  u16* __restrict__ dst, int HW) {
    __shared__ float t[32][33];
    const int b = blockIdx.z;
    const int hw0 = blockIdx.x * 32, c0 = blockIdx.y * 32;
    const float* s = src + (size_t)b * 128 * HW;
    u16* d = dst + (size_t)b * HW * 128;
    const int tx = threadIdx.x, ty = threadIdx.y;
#pragma unroll
    for (int j = 0; j < 4; ++j)
        t[ty + j * 8][tx] = s[(size_t)(c0 + ty + j * 8) * HW + hw0 + tx];
    __syncthreads();
#pragma unroll
    for (int j = 0; j < 4; ++j)
        d[(size_t)(hw0 + ty + j * 8) * 128 + c0 + tx] = f2h(t[tx][ty + j * 8]);
}

// ---------------- weight transpose: W [K x N] fp32 -> Wt [N x K] fp16 -------
// perm!=0: stored k index kk holds source channel
//   pi(kk) = (kk & ~63) + (kk&3)*16 + ((kk>>2)&15)   (matches packed C store)
__global__ void prep_wt(const float* __restrict__ W, u16* __restrict__ Wt,
                        int K, int N, int perm) {
    int idx = blockIdx.x * 256 + threadIdx.x;
    if (idx >= N * K) return;
    int nn = idx / K, kk = idx - nn * K;
    int ka = kk;
    if (perm) {
        int s = kk & 63;
        ka = (kk & ~63) + ((s & 3) << 4) + (s >> 2);
    }
    Wt[idx] = f2h(W[(size_t)ka * N + nn]);
}

// ---------------- gather / build X ------------------------------------------
// one wave per point (4 waves/block); lane handles channel pair (2l, 2l+1)
__global__ __launch_bounds__(256) void gather_build(
    const float* __restrict__ coord, const u16* __restrict__ hrT,
    const u16* __restrict__ featT, const u16* __restrict__ lrT,
    u16* __restrict__ X, float* __restrict__ rel, int p0) {
    const int wid = threadIdx.x >> 6, lane = threadIdx.x & 63;
    const int pl = blockIdx.x * 4 + wid;
    const int p = p0 + pl;
    const int b = p >> 16;  // N per batch = 65536
    const float cy = coord[(size_t)p * 2];
    const float cx = coord[(size_t)p * 2 + 1];
    const u32* hr32 = (const u32*)hrT;
    const u32* ft32 = (const u32*)featT;
    const u32* lr32 = (const u32*)lrT;

    // hr sample at unshifted coord (H=W=256)
    float fy = rintf(((cy + 1.0f) * 256.0f - 1.0f) * 0.5f);
    float fx = rintf(((cx + 1.0f) * 256.0f - 1.0f) * 0.5f);
    bool vh = (fy >= 0.0f) && (fy < 256.0f) && (fx >= 0.0f) && (fx < 256.0f);
    int iy = (int)fminf(fmaxf(fy, 0.0f), 255.0f);
    int ix = (int)fminf(fmaxf(fx, 0.0f), 255.0f);
    u32 hrv = hr32[((((size_t)b * 256 + iy) * 256 + ix) * 128 >> 1) + lane];
    if (!vh) hrv = 0u;
    const float hr_lo = h2f((u16)(hrv & 0xffffu));
    const float hr_hi = h2f((u16)(hrv >> 16));

    const size_t rowbase = (size_t)pl * 4;
#pragma unroll
    for (int s = 0; s < 4; ++s) {
        // shift order: s=0:(-1,-1) 1:(-1,+1) 2:(+1,-1) 3:(+1,+1) over (vx,vy)
        float sy = (s & 2) ? 0.015625f : -0.015625f;
        float sx = (s & 1) ? 0.015625f : -0.015625f;
        float gy = rintf(((cy + sy + 1.0f) * 64.0f - 1.0f) * 0.5f);
        float gx = rintf(((cx + sx + 1.0f) * 64.0f - 1.0f) * 0.5f);
        bool v = (gy >= 0.0f) && (gy < 64.0f) && (gx >= 0.0f) && (gx < 64.0f);
        int jy = (int)fminf(fmaxf(gy, 0.0f), 63.0f);
        int jx = (int)fminf(fmaxf(gx, 0.0f), 63.0f);
        size_t g32 = ((((size_t)b * 64 + jy) * 64 + jx) * 128 >> 1) + lane;
        u32 fv = ft32[g32];
        u32 lv = lr32[g32];
        if (!v) { fv = 0u; lv = 0u; }
        u16 d_lo = f2h(hr_lo - h2f((u16)(lv & 0xffffu)));
        u16 d_hi = f2h(hr_hi - h2f((u16)(lv >> 16)));

        u32* xr = (u32*)(X + (rowbase + s) * 384);
        xr[lane] = fv;                                    // q_feat
        xr[64 + lane] = hrv;                              // q_hr
        xr[128 + lane] = (u32)d_lo | ((u32)d_hi << 16);   // q_hr - q_lr

        if (lane == 0) {
            float qcy = v ? (-0.984375f + 0.03125f * (float)jy) : 0.0f;
            float qcx = v ? (-0.984375f + 0.03125f * (float)jx) : 0.0f;
            rel[(rowbase + s) * 2 + 0] = (cy - qcy) * 64.0f;
            rel[(rowbase + s) * 2 + 1] = (cx - qcx) * 64.0f;
        }
    }
}

// ---------------- persistent 256x256-tile 8-phase GEMM + bias + ReLU --------
// C[M x N] = relu(A[M x K] * Bt[N x K]^T + bias (+ rel rank-2 for L0))
// grid = M/256 blocks (1/CU); block cycles nt n-tiles (N = nt*256) as one
// continuous K-tile stream (global counter g), prefetch across tile bounds.
__global__ __launch_bounds__(512, 2) void gemm_f16_256(
    const u16* __restrict__ A, const u16* __restrict__ Bt,
    const float* __restrict__ bias, u16* __restrict__ C, int K, int N,
    int nt, const float* __restrict__ rel, const float* __restrict__ w0tail) {
    __shared__ __align__(16) u16 sA[2][2][8192];  // [buf][ks][256*32]
    __shared__ __align__(16) u16 sB[2][2][8192];
    const int tid = threadIdx.x;
    const int lane = tid & 63;
    const int wid = tid >> 6;
    const int r = lane & 15, q = lane >> 4;
    const int wm = wid >> 2, wn = wid & 3;

    const u32 m0 = (u32)blockIdx.x << 8;

    // staging: per half-tile [256][32] f16, 2 issues/thread (rows srow,
    // srow+128).  LDS linear dest; source chunk pre-swizzled so LDS slot
    // (R, c) holds global chunk c ^ ((R>>1)&3).
    const u32 srow = (u32)(tid >> 2);
    const u32 gchunk = (u32)((tid & 3) ^ ((tid >> 3) & 3));
    const u32 gaoff = (m0 + srow) * (u32)K + (gchunk << 3);
    const u32 gboff0 = srow * (u32)K + (gchunk << 3);

    auto stageA = [&](int kt, int ks, int buf) {
        const u16* gp = A + gaoff + (u32)((kt << 6) + (ks << 5));
        u16* lp = &sA[buf][ks][tid << 3];
        cp_async16(gp, lp);
        cp_async16(gp + ((u32)K << 7), lp + 4096);
    };
    auto stageB = [&](int tb, int kt, int ks, int buf) {
        const u16* gp = Bt + gboff0 + (u32)(tb << 8) * (u32)K +
                        (u32)((kt << 6) + (ks << 5));
        u16* lp = &sB[buf][ks][tid << 3];
        cp_async16(gp, lp);
        cp_async16(gp + ((u32)K << 7), lp + 4096);
    };

    // fragment reads: row R, want global chunk q -> slot q ^ ((R>>1)&3);
    // all row bases are multiples of 16, so swizzle reduces to (r>>1)&3.
    const int fs = (q ^ ((r >> 1) & 3)) << 3;
    const int abase = ((wm << 7) + r) * 32 + fs;  // + mi*512
    const int bbase = ((wn << 6) + r) * 32 + fs;  // + nh*1024 + ni*512

    floatx4 acc[8][4];
#pragma unroll
    for (int mi = 0; mi < 8; ++mi)
#pragma unroll
        for (int ni = 0; ni < 4; ++ni)
            acc[mi][ni] = (floatx4){0.0f, 0.0f, 0.0f, 0.0f};

    const int nk = K >> 6;
    const int total = nt * nk;
    // prologue: g=0 all 4 half-tiles, then Ah0/Ah1/Bh1 of g=1 (Bh0(1) comes
    // from the loop's phase 1).  vmcnt(6) -> oldest 8 loads (= g0) landed.
    stageA(0, 0, 0);
    stageA(0, 1, 0);
    stageB(0, 0, 0, 0);
    stageB(0, 0, 1, 0);
    stageA(1, 0, 1);
    stageA(1, 1, 1);
    stageB(0, 1, 1, 1);
    asm volatile("s_waitcnt vmcnt(6)");
    __builtin_amdgcn_s_barrier();

    for (int t = 0; t < nt; ++t) {
        for (int kt = 0; kt < nk; ++kt) {
            const int cur = kt & 1, nxt = cur ^ 1;
            const int g = t * nk + kt;
            const bool h1 = (g + 1) < total;
            const bool h2 = (g + 2) < total;
            const int in1 = (kt + 1) < nk;
            const int tb1 = in1 ? t : t + 1;
            const int kt1 = in1 ? kt + 1 : 0;
            int kt2 = kt + 2, tb2 = t;
            if (kt2 >= nk) { kt2 -= nk; tb2 = t + 1; }
            half8 a0[8], a1[8], bf[2];
            // -- phase 1: read A(ks0)+B(nh0,ks0); stage Bh0(g+1); mfma
#pragma unroll
            for (int mi = 0; mi < 8; ++mi)
                a0[mi] = *(const half8*)&sA[cur][0][abase + (mi << 9)];
#pragma unroll
            for (int ni = 0; ni < 2; ++ni)
                bf[ni] = *(const half8*)&sB[cur][0][bbase + (ni << 9)];
            if (h1) stageB(tb1, kt1, 0, nxt);
            __builtin_amdgcn_s_barrier();
            asm volatile("s_waitcnt lgkmcnt(0)");
            __builtin_amdgcn_s_setprio(1);
#pragma unroll
            for (int mi = 0; mi < 8; ++mi)
#pragma unroll
                for (int ni = 0; ni < 2; ++ni)
                    acc[mi][ni] = __builtin_amdgcn_mfma_f32_16x16x32_f16(
                        a0[mi], bf[ni], acc[mi][ni], 0, 0, 0);
            __builtin_amdgcn_s_setprio(0);
            __builtin_amdgcn_s_barrier();
            // -- phase 2: read A(ks1)+B(nh0,ks1); stage Ah0(g+2); mfma
#pragma unroll
            for (int mi = 0; mi < 8; ++mi)
                a1[mi] = *(const half8*)&sA[cur][1][abase + (mi << 9)];
#pragma unroll
            for (int ni = 0; ni < 2; ++ni)
                bf[ni] = *(const half8*)&sB[cur][1][bbase + (ni << 9)];
            if (h2) stageA(kt2, 0, cur);
            __builtin_amdgcn_s_barrier();
            asm volatile("s_waitcnt lgkmcnt(0)");
            __builtin_amdgcn_s_setprio(1);
#pragma unroll
            for (int mi = 0; mi < 8; ++mi)
#pragma unroll
                for (int ni = 0; ni < 2; ++ni)
                    acc[mi][ni] = __builtin_amdgcn_mfma_f32_16x16x32_f16(
                        a1[mi], bf[ni], acc[mi][ni], 0, 0, 0);
            __builtin_amdgcn_s_setprio(0);
            __builtin_amdgcn_s_barrier();
            // -- phase 3: read B(nh1,ks1); stage Ah1(g+2); mfma
#pragma unroll
            for (int ni = 0; ni < 2; ++ni)
                bf[ni] = *(const half8*)&sB[cur][1][bbase + 1024 + (ni << 9)];
            if (h2) stageA(kt2, 1, cur);
            __builtin_amdgcn_s_barrier();
            asm volatile("s_waitcnt lgkmcnt(0)");
            __builtin_amdgcn_s_setprio(1);
#pragma unroll
            for (int mi = 0; mi < 8; ++mi)
#pragma unroll
                for (int ni = 0; ni < 2; ++ni)
                    acc[mi][2 + ni] = __builtin_amdgcn_mfma_f32_16x16x32_f16(
                        a1[mi], bf[ni], acc[mi][2 + ni], 0, 0, 0);
            __builtin_amdgcn_s_setprio(0);
            __builtin_amdgcn_s_barrier();
            // -- phase 4: read B(nh1,ks0); stage Bh1(g+2); mfma; counted wait
#pragma unroll
            for (int ni = 0; ni < 2; ++ni)
                bf[ni] = *(const half8*)&sB[cur][0][bbase + 1024 + (ni << 9)];
            if (h2) stageB(tb2, kt2, 1, cur);
            __builtin_amdgcn_s_barrier();
            asm volatile("s_waitcnt lgkmcnt(0)");
            __builtin_amdgcn_s_setprio(1);
#pragma unroll
            for (int mi = 0; mi < 8; ++mi)
#pragma unroll
                for (int ni = 0; ni < 2; ++ni)
                    acc[mi][2 + ni] = __builtin_amdgcn_mfma_f32_16x16x32_f16(
                        a0[mi], bf[ni], acc[mi][2 + ni], 0, 0, 0);
            __builtin_amdgcn_s_setprio(0);
            if (h2) {
                asm volatile("s_waitcnt vmcnt(6)");
            } else {
                asm volatile("s_waitcnt vmcnt(0)");
            }
            __builtin_amdgcn_s_barrier();
        }

        // ---- per-tile epilogue (registers + global only; overlaps the
        //      in-flight DMA prefetch of tiles t+1/t+2) ----
        const int n0 = t << 8;
        float bias_v[4], w0a[4], w0b[4];
#pragma unroll
        for (int nig = 0; nig < 4; ++nig) {
            int col = n0 + (wn << 6) + nig * 16 + r;
            bias_v[nig] = bias[col];
            w0a[nig] = rel ? w0tail[col] : 0.0f;
            w0b[nig] = rel ? w0tail[N + col] : 0.0f;
        }
#pragma unroll
        for (int mi = 0; mi < 8; ++mi) {
#pragma unroll
            for (int rr = 0; rr < 4; ++rr) {
                u32 row = m0 + (u32)(wm << 7) + (u32)(mi << 4) +
                          (u32)(q << 2) + (u32)rr;
                float rl0 = 0.0f, rl1 = 0.0f;
                if (rel) {
                    floatx2 rl = *(const floatx2*)&rel[(size_t)row * 2];
                    rl0 = rl[0];
                    rl1 = rl[1];
                }
                u32 pk[2];
#pragma unroll
                for (int h = 0; h < 2; ++h) {
                    u32 w = 0;
#pragma unroll
                    for (int j = 0; j < 2; ++j) {
                        int nig = h * 2 + j;
                        float v = acc[mi][nig][rr] + bias_v[nig];
                        if (rel) v += rl0 * w0a[nig] + rl1 * w0b[nig];
                        v = fmaxf(v, 0.0f);
                        w |= (u32)f2h(v) << (16 * j);
                    }
                    pk[h] = w;
                }
                *(u32x2*)(C + row * (u32)N + (u32)(n0 + (wn << 6) + (r << 2))) =
                    (u32x2){pk[0], pk[1]};
            }
        }
#pragma unroll
        for (int mi = 0; mi < 8; ++mi)
#pragma unroll
            for (int ni = 0; ni < 4; ++ni)
                acc[mi][ni] = (floatx4){0.0f, 0.0f, 0.0f, 0.0f};
    }
}

// ---------------- round-6 128x128 GEMM (kept for L3 / fallback) -------------
__global__ __launch_bounds__(256, 3) void gemm_f16(
    const u16* __restrict__ A, const u16* __restrict__ Bt,
    const float* __restrict__ bias, u16* __restrict__ C, int K, int N,
    int lognb, const float* __restrict__ rel, const float* __restrict__ w0tail) {
    __shared__ __align__(16) u16 As[2][128 * 64];
    __shared__ __align__(16) u16 Bs[128 * 64];
    const int tid = threadIdx.x;
    const int lane = tid & 63;
    const int wid = tid >> 6;
    const int r = lane & 15, q = lane >> 4;
    const int wm = (wid & 1) << 6, wn = (wid >> 1) << 6;

    const int g = blockIdx.x;
    const int n_idx = (g >> 3) & ((1 << lognb) - 1);
    const int m_idx = (g & 7) + ((g >> (3 + lognb)) << 3);
    const int n0 = n_idx << 7;
    const u32 m0 = (u32)m_idx << 7;

    const int srow = tid >> 3;
    const int schunk = (tid & 7) ^ (srow & 7);
    const u32 gaoff = (m0 + (u32)srow) * (u32)K + ((u32)schunk << 3);
    const u32 gboff = (u32)(n0 + srow) * (u32)K + ((u32)schunk << 3);

    auto stageA = [&](int kt, int buf) {
        const u16* gak = A + gaoff + (kt << 6);
        u16* la = &As[buf][tid * 8];
#pragma unroll
        for (int i = 0; i < 4; ++i)
            cp_async16(gak + (u32)(i << 5) * (u32)K, la + (i << 11));
    };

    u32x4 breg[4];
    auto loadB = [&](int kt) {
        const u16* gbk = Bt + gboff + (kt << 6);
#pragma unroll
        for (int i = 0; i < 4; ++i)
            breg[i] = *(const u32x4*)(gbk + (u32)(i << 5) * (u32)K);
    };
    auto writeB = [&]() {
        u16* lb = &Bs[tid * 8];
#pragma unroll
        for (int i = 0; i < 4; ++i)
            *(u32x4*)(lb + (i << 11)) = breg[i];
    };

    const int cx = (q ^ (r & 7)) << 3;
    const int arow = (wm + r) << 6, brow = (wn + r) << 6;

    floatx4 acc[4][4];
#pragma unroll
    for (int mi = 0; mi < 4; ++mi)
#pragma unroll
        for (int ni = 0; ni < 4; ++ni)
            acc[mi][ni] = (floatx4){0.0f, 0.0f, 0.0f, 0.0f};

    const int nk = K >> 6;
    loadB(0);
    stageA(0, 0);
    writeB();
    __syncthreads();

    for (int kt = 0; kt < nk; ++kt) {
        const int cur = kt & 1;
        const bool pf = (kt + 1 < nk);
        if (pf) {
            loadB(kt + 1);
            stageA(kt + 1, cur ^ 1);
        }
#pragma unroll
        for (int ks = 0; ks < 2; ++ks) {
            half8 af[4], bfr[4];
#pragma unroll
            for (int mi = 0; mi < 4; ++mi)
                af[mi] = *(const half8*)&As[cur][arow + (mi << 10) + (cx ^ (ks << 5))];
#pragma unroll
            for (int ni = 0; ni < 4; ++ni)
                bfr[ni] = *(const half8*)&Bs[brow + (ni << 10) + (cx ^ (ks << 5))];
#pragma unroll
            for (int mi = 0; mi < 4; ++mi)
#pragma unroll
                for (int ni = 0; ni < 4; ++ni)
                    acc[mi][ni] = __builtin_amdgcn_mfma_f32_16x16x32_f16(
                        af[mi], bfr[ni], acc[mi][ni], 0, 0, 0);
        }
        if (pf) {
            __syncthreads();
            writeB();
            __syncthreads();
        }
    }

    float bias_v[4], w0a[4], w0b[4];
#pragma unroll
    for (int ni = 0; ni < 4; ++ni) {
        int col = n0 + wn + ni * 16 + r;
        bias_v[ni] = bias[col];
        w0a[ni] = rel ? w0tail[col] : 0.0f;
        w0b[ni] = rel ? w0tail[N + col] : 0.0f;
    }
#pragma unroll
    for (int mi = 0; mi < 4; ++mi) {
#pragma unroll
        for (int rr = 0; rr < 4; ++rr) {
            u32 row = m0 + wm + mi * 16 + q * 4 + rr;
            float rl0 = 0.0f, rl1 = 0.0f;
            if (rel) {
                floatx2 rl = *(const floatx2*)&rel[(size_t)row * 2];
                rl0 = rl[0];
                rl1 = rl[1];
            }
            u32 pk[2];
#pragma unroll
            for (int h = 0; h < 2; ++h) {
                u32 w = 0;
#pragma unroll
                for (int j = 0; j < 2; ++j) {
                    int ni = h * 2 + j;
                    float v = acc[mi][ni][rr] + bias_v[ni];
                    if (rel) v += rl0 * w0a[ni] + rl1 * w0b[ni];
                    v = fmaxf(v, 0.0f);
                    w |= (u32)f2h(v) << (16 * j);
                }
                pk[h] = w;
            }
            *(u32x2*)(C + row * (u32)N + (u32)(n0 + wn + (r << 2))) =
                (u32x2){pk[0], pk[1]};
        }
    }
}

// ---------------- L4 (128 -> 2) + softmax combine ---------------------------
// one wave per point; A3 is packed-permuted -> index W4 through pi()
__global__ __launch_bounds__(256) void l4_combine(
    const u16* __restrict__ A3, const float* __restrict__ W4,
    const float* __restrict__ b4, float* __restrict__ out, int p0) {
    const int wid = threadIdx.x >> 6, lane = threadIdx.x & 63;
    const int pl = blockIdx.x * 4 + wid;
    const int p2 = lane * 2;
    const int s0 = p2 & 63, bb = p2 & ~63;
    const int k0 = bb + ((s0 & 3) << 4) + (s0 >> 2);
    const int s1 = s0 + 1;
    const int k1 = bb + ((s1 & 3) << 4) + (s1 >> 2);
    const float w00 = W4[k0 * 2], w01 = W4[k0 * 2 + 1];
    const float w10 = W4[k1 * 2], w11 = W4[k1 * 2 + 1];
    float P0[4], P1[4];
#pragma unroll
    for (int s = 0; s < 4; ++s) {
        size_t rowoff = ((size_t)pl * 4 + s) * 128 + p2;
        u32 av = *(const u32*)(A3 + rowoff);
        float a0 = h2f((u16)(av & 0xffffu));
        float a1 = h2f((u16)(av >> 16));
        float d0 = a0 * w00 + a1 * w10;
        float d1 = a0 * w01 + a1 * w11;
#pragma unroll
        for (int m = 32; m >= 1; m >>= 1) {
            d0 += __shfl_xor(d0, m, 64);
            d1 += __shfl_xor(d1, m, 64);
        }
        P0[s] = d0 + b4[0];
        P1[s] = d1 + b4[1];
    }
    if (lane == 0) {
        float mx = fmaxf(fmaxf(P1[0], P1[1]), fmaxf(P1[2], P1[3]));
        float e0 = __expf(P1[0] - mx), e1 = __expf(P1[1] - mx);
        float e2 = __expf(P1[2] - mx), e3 = __expf(P1[3] - mx);
        float se = e0 + e1 + e2 + e3;
        out[p0 + pl] = (P0[0] * e0 + P0[1] * e1 + P0[2] * e2 + P0[3] * e3) / se;
    }
}

// ---------------------------------------------------------------------------
extern "C" void kernel_launch(void* const* d_in, const int* in_sizes, int n_in,
                              void* d_out, int out_size, void* d_ws,
                              size_t ws_size, hipStream_t stream) {
    const float* feat = (const float*)d_in[0];
    const float* coord = (const float*)d_in[1];
    const float* hr = (const float*)d_in[2];
    const float* lr = (const float*)d_in[3];
    const float* W0 = (const float*)d_in[4];
    const float* b0 = (const float*)d_in[5];
    const float* W1 = (const float*)d_in[6];
    const float* b1 = (const float*)d_in[7];
    const float* W2 = (const float*)d_in[8];
    const float* b2 = (const float*)d_in[9];
    const float* W3 = (const float*)d_in[10];
    const float* b3 = (const float*)d_in[11];
    const float* W4 = (const float*)d_in[12];
    const float* b4 = (const float*)d_in[13];
    float* out = (float*)d_out;

    char* base = (char*)d_ws;
    size_t off = 0;
    auto carve = [&](size_t bytes) -> char* {
        char* p = base + off;
        off += (bytes + 255) & ~(size_t)255;
        return p;
    };

    u16* hrT = (u16*)carve(4ull * 65536 * 128 * 2);   // [4][256][256][128] f16
    u16* featT = (u16*)carve(4ull * 4096 * 128 * 2);  // [4][64][64][128] f16
    u16* lrT = (u16*)carve(4ull * 4096 * 128 * 2);
    u16* Wt0 = (u16*)carve(1024ull * 384 * 2);        // [N][K] f16
    u16* Wt1 = (u16*)carve(512ull * 1024 * 2);
    u16* Wt2 = (u16*)carve(256ull * 512 * 2);
    u16* Wt3 = (u16*)carve(128ull * 256 * 2);
    const size_t fixed = off;

    const size_t R = 1048576ull;  // 262144 points * 4 shifts
    // c = 16 minimum: chunk working set (X 50MB + A0 134MB) stays inside the
    // 256MB L3 so inter-layer activations never round-trip HBM.
    int c = 16;
    for (; c < 8192; c *= 2) {
        size_t Rc = R / c;
        size_t need = fixed;
        size_t sizes[3] = {Rc * 1024, Rc * 8, Rc * 2048};
        for (int i = 0; i < 3; ++i) need += (sizes[i] + 255) & ~(size_t)255;
        if (need <= ws_size) break;
    }
    const size_t Rc = R / c;
    const int Pc = (int)(262144 / c);

    char* R1 = carve(Rc * 1024);
    float* rel = (float*)carve(Rc * 8);
    char* R2 = carve(Rc * 2048);
    u16* X = (u16*)R1;                   // [Rc][384] f16 (dead after L0)
    u16* A1 = (u16*)R1;                  // [Rc][512]  (overwrites X in L1)
    u16* A0 = (u16*)R2;                  // [Rc][1024] (dead after L1)
    u16* A2 = (u16*)R2;                  // [Rc][256]  (overwrites A0 in L2)
    u16* A3 = (u16*)(R2 + Rc * 512);     // [Rc][128]  (disjoint from A2)

    transpose_chw_hwc<<<dim3(2048, 4, 4), dim3(32, 8), 0, stream>>>(hr, hrT, 65536);
    transpose_chw_hwc<<<dim3(128, 4, 4), dim3(32, 8), 0, stream>>>(feat, featT, 4096);
    transpose_chw_hwc<<<dim3(128, 4, 4), dim3(32, 8), 0, stream>>>(lr, lrT, 4096);
    prep_wt<<<(1024 * 384 + 255) / 256, 256, 0, stream>>>(W0, Wt0, 384, 1024, 0);
    prep_wt<<<(512 * 1024 + 255) / 256, 256, 0, stream>>>(W1, Wt1, 1024, 512, 1);
    prep_wt<<<(256 * 512 + 255) / 256, 256, 0, stream>>>(W2, Wt2, 512, 256, 1);
    prep_wt<<<(128 * 256 + 255) / 256, 256, 0, stream>>>(W3, Wt3, 256, 128, 1);

    const int mt1 = (int)(Rc / 128);  // 128-row tiles (old kernel)
    const int mt2 = (int)(Rc / 256);  // 256-row tiles (persistent kernel)
    const bool use256 = (Rc % 2048ull) == 0;
    for (int ci = 0; ci < c; ++ci) {
        const int p0 = ci * Pc;
        gather_build<<<Pc / 4, 256, 0, stream>>>(coord, hrT, featT, lrT, X, rel, p0);
        if (use256) {
            gemm_f16_256<<<mt2, 512, 0, stream>>>(X, Wt0, b0, A0, 384, 1024,
                                                  4, rel, W0 + 384 * 1024);
            gemm_f16_256<<<mt2, 512, 0, stream>>>(A0, Wt1, b1, A1, 1024, 512,
                                                  2, nullptr, nullptr);
            gemm_f16_256<<<mt2, 512, 0, stream>>>(A1, Wt2, b2, A2, 512, 256,
                                                  1, nullptr, nullptr);
        } else {
            gemm_f16<<<mt1 * 8, 256, 0, stream>>>(X, Wt0, b0, A0, 384, 1024, 3,
                                                  rel, W0 + 384 * 1024);
            gemm_f16<<<mt1 * 4, 256, 0, stream>>>(A0, Wt1, b1, A1, 1024, 512, 2,
                                                  nullptr, nullptr);
            gemm_f16<<<mt1 * 2, 256, 0, stream>>>(A1, Wt2, b2, A2, 512, 256, 1,
                                                  nullptr, nullptr);
        }
        gemm_f16<<<mt1 * 1, 256, 0, stream>>>(A2, Wt3, b3, A3, 256, 128, 0,
                                              nullptr, nullptr);
        l4_combine<<<Pc / 4, 256, 0, stream>>>(A3, W4, b4, out, p0);
    }
}

// Round 4
// 3718.134 us; speedup vs baseline: 1.4293x; 1.4293x over previous
//
#include <hip/hip_runtime.h>
#include <cstdint>
#include <cstddef>

// ---------------------------------------------------------------------------
// JIIF fused pipeline (round 10 = round 8 revert + per-layer kernel routing):
//   - round-9 persistence REVERTED: it re-staged A per n-tile (4x L2-miss
//     traffic, FETCH 37->197MB measured) and 1 block/CU couldn't hide it.
//   - kernel routing by K-depth (measured r0-r2): L0 (nk=6) -> 128x128
//     kernel, 3 blocks/CU (shallow pipeline, ramp hidden by co-resident
//     blocks: 1.44 ns/row vs 1.70 on 256x256); L1 (nk=16) / L2 (nk=8) ->
//     256x256 8-phase kernel (deep pipeline pays at long K: <=0.85 ns/row).
//   - c=16 chunking (L3-resident activations), XOR-swizzled LDS (0 bank
//     conflicts), XCD-aware decode, counted vmcnt(6), tail-guarded stages.
// Rows ordered point-major: row = point*4 + shift.
// ---------------------------------------------------------------------------

typedef unsigned short u16;
typedef unsigned int u32;
typedef _Float16 half8 __attribute__((ext_vector_type(8)));
typedef float floatx4 __attribute__((ext_vector_type(4)));
typedef float floatx2 __attribute__((ext_vector_type(2)));
typedef u32 u32x2 __attribute__((ext_vector_type(2)));
typedef u32 u32x4 __attribute__((ext_vector_type(4)));

__device__ __forceinline__ u16 f2h(float x) {
    _Float16 h = (_Float16)x;
    return __builtin_bit_cast(unsigned short, h);
}
__device__ __forceinline__ float h2f(u16 u) {
    return (float)__builtin_bit_cast(_Float16, u);
}

// async 16B global -> LDS (wave-uniform LDS base + lane*16)
__device__ __forceinline__ void cp_async16(const void* gsrc, void* lds) {
#if defined(__has_builtin) && __has_builtin(__builtin_amdgcn_global_load_lds)
    __builtin_amdgcn_global_load_lds(
        (__attribute__((address_space(1))) void*)(uintptr_t)gsrc,
        (__attribute__((address_space(3))) void*)(uint32_t)(uintptr_t)lds,
        16, 0, 0);
#else
    *(u32x4*)lds = *(const u32x4*)gsrc;
#endif
}

// ---------------- transpose [B][C=128][HW] fp32 -> [B][HW][C] fp16 ----------
__global__ void transpose_chw_hwc(const float* __restrict__ src,
                                  u16* __restrict__ dst, int HW) {
    __shared__ float t[32][33];
    const int b = blockIdx.z;
    const int hw0 = blockIdx.x * 32, c0 = blockIdx.y * 32;
    const float* s = src + (size_t)b * 128 * HW;
    u16* d = dst + (size_t)b * HW * 128;
    const int tx = threadIdx.x, ty = threadIdx.y;
#pragma unroll
    for (int j = 0; j < 4; ++j)
        t[ty + j * 8][tx] = s[(size_t)(c0 + ty + j * 8) * HW + hw0 + tx];
    __syncthreads();
#pragma unroll
    for (int j = 0; j < 4; ++j)
        d[(size_t)(hw0 + ty + j * 8) * 128 + c0 + tx] = f2h(t[tx][ty + j * 8]);
}

// ---------------- weight transpose: W [K x N] fp32 -> Wt [N x K] fp16 -------
// perm!=0: stored k index kk holds source channel
//   pi(kk) = (kk & ~63) + (kk&3)*16 + ((kk>>2)&15)   (matches packed C store)
__global__ void prep_wt(const float* __restrict__ W, u16* __restrict__ Wt,
                        int K, int N, int perm) {
    int idx = blockIdx.x * 256 + threadIdx.x;
    if (idx >= N * K) return;
    int nn = idx / K, kk = idx - nn * K;
    int ka = kk;
    if (perm) {
        int s = kk & 63;
        ka = (kk & ~63) + ((s & 3) << 4) + (s >> 2);
    }
    Wt[idx] = f2h(W[(size_t)ka * N + nn]);
}

// ---------------- gather / build X ------------------------------------------
// one wave per point (4 waves/block); lane handles channel pair (2l, 2l+1)
__global__ __launch_bounds__(256) void gather_build(
    const float* __restrict__ coord, const u16* __restrict__ hrT,
    const u16* __restrict__ featT, const u16* __restrict__ lrT,
    u16* __restrict__ X, float* __restrict__ rel, int p0) {
    const int wid = threadIdx.x >> 6, lane = threadIdx.x & 63;
    const int pl = blockIdx.x * 4 + wid;
    const int p = p0 + pl;
    const int b = p >> 16;  // N per batch = 65536
    const float cy = coord[(size_t)p * 2];
    const float cx = coord[(size_t)p * 2 + 1];
    const u32* hr32 = (const u32*)hrT;
    const u32* ft32 = (const u32*)featT;
    const u32* lr32 = (const u32*)lrT;

    // hr sample at unshifted coord (H=W=256)
    float fy = rintf(((cy + 1.0f) * 256.0f - 1.0f) * 0.5f);
    float fx = rintf(((cx + 1.0f) * 256.0f - 1.0f) * 0.5f);
    bool vh = (fy >= 0.0f) && (fy < 256.0f) && (fx >= 0.0f) && (fx < 256.0f);
    int iy = (int)fminf(fmaxf(fy, 0.0f), 255.0f);
    int ix = (int)fminf(fmaxf(fx, 0.0f), 255.0f);
    u32 hrv = hr32[((((size_t)b * 256 + iy) * 256 + ix) * 128 >> 1) + lane];
    if (!vh) hrv = 0u;
    const float hr_lo = h2f((u16)(hrv & 0xffffu));
    const float hr_hi = h2f((u16)(hrv >> 16));

    const size_t rowbase = (size_t)pl * 4;
#pragma unroll
    for (int s = 0; s < 4; ++s) {
        // shift order: s=0:(-1,-1) 1:(-1,+1) 2:(+1,-1) 3:(+1,+1) over (vx,vy)
        float sy = (s & 2) ? 0.015625f : -0.015625f;
        float sx = (s & 1) ? 0.015625f : -0.015625f;
        float gy = rintf(((cy + sy + 1.0f) * 64.0f - 1.0f) * 0.5f);
        float gx = rintf(((cx + sx + 1.0f) * 64.0f - 1.0f) * 0.5f);
        bool v = (gy >= 0.0f) && (gy < 64.0f) && (gx >= 0.0f) && (gx < 64.0f);
        int jy = (int)fminf(fmaxf(gy, 0.0f), 63.0f);
        int jx = (int)fminf(fmaxf(gx, 0.0f), 63.0f);
        size_t g32 = ((((size_t)b * 64 + jy) * 64 + jx) * 128 >> 1) + lane;
        u32 fv = ft32[g32];
        u32 lv = lr32[g32];
        if (!v) { fv = 0u; lv = 0u; }
        u16 d_lo = f2h(hr_lo - h2f((u16)(lv & 0xffffu)));
        u16 d_hi = f2h(hr_hi - h2f((u16)(lv >> 16)));

        u32* xr = (u32*)(X + (rowbase + s) * 384);
        xr[lane] = fv;                                    // q_feat
        xr[64 + lane] = hrv;                              // q_hr
        xr[128 + lane] = (u32)d_lo | ((u32)d_hi << 16);   // q_hr - q_lr

        if (lane == 0) {
            float qcy = v ? (-0.984375f + 0.03125f * (float)jy) : 0.0f;
            float qcx = v ? (-0.984375f + 0.03125f * (float)jx) : 0.0f;
            rel[(rowbase + s) * 2 + 0] = (cy - qcy) * 64.0f;
            rel[(rowbase + s) * 2 + 1] = (cx - qcx) * 64.0f;
        }
    }
}

// ---------------- 256x256-tile 8-phase GEMM + bias + ReLU -------------------
// C[M x N] = relu(A[M x K] * Bt[N x K]^T + bias (+ rel rank-2 for L0))
// 512 threads = 8 waves (2M x 4N), per-wave 128x64 output, BK = 64 as two
// K-half buffers [256][32] per operand.  Counted vmcnt(6), 1 block/CU.
// Best for long K (nk >= 8); short-K layers route to gemm_f16 instead.
__global__ __launch_bounds__(512, 2) void gemm_f16_256(
    const u16* __restrict__ A, const u16* __restrict__ Bt,
    const float* __restrict__ bias, u16* __restrict__ C, int K, int N,
    int lognb, const float* __restrict__ rel, const float* __restrict__ w0tail) {
    __shared__ __align__(16) u16 sA[2][2][8192];  // [buf][ks][256*32]
    __shared__ __align__(16) u16 sB[2][2][8192];
    const int tid = threadIdx.x;
    const int lane = tid & 63;
    const int wid = tid >> 6;
    const int r = lane & 15, q = lane >> 4;
    const int wm = wid >> 2, wn = wid & 3;

    // XCD-aware decode: blocks sharing an m-tile have equal g%8 -> same XCD.
    const int g = blockIdx.x;
    const int n_idx = (g >> 3) & ((1 << lognb) - 1);
    const int m_idx = (g & 7) + ((g >> (3 + lognb)) << 3);
    const int n0 = n_idx << 8;
    const u32 m0 = (u32)m_idx << 8;

    // staging: per half-tile [256][32] f16, 2 issues/thread (rows srow,
    // srow+128).  LDS linear dest; source chunk pre-swizzled so LDS slot
    // (R, c) holds global chunk c ^ ((R>>1)&3).
    const u32 srow = (u32)(tid >> 2);
    const u32 gchunk = (u32)((tid & 3) ^ ((tid >> 3) & 3));
    const u32 gaoff = (m0 + srow) * (u32)K + (gchunk << 3);
    const u32 gboff = ((u32)n0 + srow) * (u32)K + (gchunk << 3);

    auto stageA = [&](int kt, int ks, int buf) {
        const u16* gp = A + gaoff + (u32)((kt << 6) + (ks << 5));
        u16* lp = &sA[buf][ks][tid << 3];
        cp_async16(gp, lp);
        cp_async16(gp + ((u32)K << 7), lp + 4096);
    };
    auto stageB = [&](int kt, int ks, int buf) {
        const u16* gp = Bt + gboff + (u32)((kt << 6) + (ks << 5));
        u16* lp = &sB[buf][ks][tid << 3];
        cp_async16(gp, lp);
        cp_async16(gp + ((u32)K << 7), lp + 4096);
    };

    // fragment reads: row R, want global chunk q -> slot q ^ ((R>>1)&3);
    // all row bases are multiples of 16, so swizzle reduces to (r>>1)&3.
    const int fs = (q ^ ((r >> 1) & 3)) << 3;
    const int abase = ((wm << 7) + r) * 32 + fs;  // + mi*512
    const int bbase = ((wn << 6) + r) * 32 + fs;  // + nh*1024 + ni*512

    floatx4 acc[8][4];
#pragma unroll
    for (int mi = 0; mi < 8; ++mi)
#pragma unroll
        for (int ni = 0; ni < 4; ++ni)
            acc[mi][ni] = (floatx4){0.0f, 0.0f, 0.0f, 0.0f};

    const int nk = K >> 6;
    // prologue: T0 all 4 half-tiles, then Ah0/Ah1/Bh1 of T1 (Bh0(T1) comes
    // from the loop's phase 1).  vmcnt(6) -> oldest 8 loads (= T0) landed.
    stageA(0, 0, 0);
    stageA(0, 1, 0);
    stageB(0, 0, 0);
    stageB(0, 1, 0);
    const int k1 = (nk > 1) ? 1 : 0;
    stageA(k1, 0, 1);
    stageA(k1, 1, 1);
    stageB(k1, 1, 1);
    asm volatile("s_waitcnt vmcnt(6)");
    __builtin_amdgcn_s_barrier();

    for (int kt = 0; kt < nk; ++kt) {
        const int cur = kt & 1, nxt = cur ^ 1;
        const bool p1 = (kt + 1) < nk;
        const bool p2 = (kt + 2) < nk;
        half8 a0[8], a1[8], bf[2];
        // ---- phase 1: read A(ks0)+B(nh0,ks0); stage Bh0(T+1); mfma(nh0,ks0)
#pragma unroll
        for (int mi = 0; mi < 8; ++mi)
            a0[mi] = *(const half8*)&sA[cur][0][abase + (mi << 9)];
#pragma unroll
        for (int ni = 0; ni < 2; ++ni)
            bf[ni] = *(const half8*)&sB[cur][0][bbase + (ni << 9)];
        if (p1) stageB(kt + 1, 0, nxt);
        __builtin_amdgcn_s_barrier();
        asm volatile("s_waitcnt lgkmcnt(0)");
        __builtin_amdgcn_s_setprio(1);
#pragma unroll
        for (int mi = 0; mi < 8; ++mi)
#pragma unroll
            for (int ni = 0; ni < 2; ++ni)
                acc[mi][ni] = __builtin_amdgcn_mfma_f32_16x16x32_f16(
                    a0[mi], bf[ni], acc[mi][ni], 0, 0, 0);
        __builtin_amdgcn_s_setprio(0);
        __builtin_amdgcn_s_barrier();
        // ---- phase 2: read A(ks1)+B(nh0,ks1); stage Ah0(T+2); mfma(nh0,ks1)
#pragma unroll
        for (int mi = 0; mi < 8; ++mi)
            a1[mi] = *(const half8*)&sA[cur][1][abase + (mi << 9)];
#pragma unroll
        for (int ni = 0; ni < 2; ++ni)
            bf[ni] = *(const half8*)&sB[cur][1][bbase + (ni << 9)];
        if (p2) stageA(kt + 2, 0, cur);
        __builtin_amdgcn_s_barrier();
        asm volatile("s_waitcnt lgkmcnt(0)");
        __builtin_amdgcn_s_setprio(1);
#pragma unroll
        for (int mi = 0; mi < 8; ++mi)
#pragma unroll
            for (int ni = 0; ni < 2; ++ni)
                acc[mi][ni] = __builtin_amdgcn_mfma_f32_16x16x32_f16(
                    a1[mi], bf[ni], acc[mi][ni], 0, 0, 0);
        __builtin_amdgcn_s_setprio(0);
        __builtin_amdgcn_s_barrier();
        // ---- phase 3: read B(nh1,ks1); stage Ah1(T+2); mfma(nh1,ks1)
#pragma unroll
        for (int ni = 0; ni < 2; ++ni)
            bf[ni] = *(const half8*)&sB[cur][1][bbase + 1024 + (ni << 9)];
        if (p2) stageA(kt + 2, 1, cur);
        __builtin_amdgcn_s_barrier();
        asm volatile("s_waitcnt lgkmcnt(0)");
        __builtin_amdgcn_s_setprio(1);
#pragma unroll
        for (int mi = 0; mi < 8; ++mi)
#pragma unroll
            for (int ni = 0; ni < 2; ++ni)
                acc[mi][2 + ni] = __builtin_amdgcn_mfma_f32_16x16x32_f16(
                    a1[mi], bf[ni], acc[mi][2 + ni], 0, 0, 0);
        __builtin_amdgcn_s_setprio(0);
        __builtin_amdgcn_s_barrier();
        // ---- phase 4: read B(nh1,ks0); stage Bh1(T+2); mfma(nh1,ks0);
        //      counted vmcnt while a +2 tile is in flight, else cheap drain
        //      (tile kt+1's loads finished issuing at this tile's phase 1).
#pragma unroll
        for (int ni = 0; ni < 2; ++ni)
            bf[ni] = *(const half8*)&sB[cur][0][bbase + 1024 + (ni << 9)];
        if (p2) stageB(kt + 2, 1, cur);
        __builtin_amdgcn_s_barrier();
        asm volatile("s_waitcnt lgkmcnt(0)");
        __builtin_amdgcn_s_setprio(1);
#pragma unroll
        for (int mi = 0; mi < 8; ++mi)
#pragma unroll
            for (int ni = 0; ni < 2; ++ni)
                acc[mi][2 + ni] = __builtin_amdgcn_mfma_f32_16x16x32_f16(
                    a0[mi], bf[ni], acc[mi][2 + ni], 0, 0, 0);
        __builtin_amdgcn_s_setprio(0);
        if (p2) {
            asm volatile("s_waitcnt vmcnt(6)");
        } else {
            asm volatile("s_waitcnt vmcnt(0)");
        }
        __builtin_amdgcn_s_barrier();
    }

    // epilogue: C/D layout col=lane&15 (=r), row=q*4+reg.  Packed-permuted
    // store: stored offset r*4+nig holds actual channel nig*16+r (8B dwordx2).
    float bias_v[4], w0a[4], w0b[4];
#pragma unroll
    for (int nig = 0; nig < 4; ++nig) {
        int col = n0 + (wn << 6) + nig * 16 + r;
        bias_v[nig] = bias[col];
        w0a[nig] = rel ? w0tail[col] : 0.0f;
        w0b[nig] = rel ? w0tail[N + col] : 0.0f;
    }
#pragma unroll
    for (int mi = 0; mi < 8; ++mi) {
#pragma unroll
        for (int rr = 0; rr < 4; ++rr) {
            u32 row = m0 + (u32)(wm << 7) + (u32)(mi << 4) + (u32)(q << 2) +
                      (u32)rr;
            float rl0 = 0.0f, rl1 = 0.0f;
            if (rel) {
                floatx2 rl = *(const floatx2*)&rel[(size_t)row * 2];
                rl0 = rl[0];
                rl1 = rl[1];
            }
            u32 pk[2];
#pragma unroll
            for (int h = 0; h < 2; ++h) {
                u32 w = 0;
#pragma unroll
                for (int j = 0; j < 2; ++j) {
                    int nig = h * 2 + j;
                    float v = acc[mi][nig][rr] + bias_v[nig];
                    if (rel) v += rl0 * w0a[nig] + rl1 * w0b[nig];
                    v = fmaxf(v, 0.0f);
                    w |= (u32)f2h(v) << (16 * j);
                }
                pk[h] = w;
            }
            *(u32x2*)(C + row * (u32)N + (u32)(n0 + (wn << 6) + (r << 2))) =
                (u32x2){pk[0], pk[1]};
        }
    }
}

// ---------------- 128x128 GEMM (short-K layers: L0, L3) ---------------------
__global__ __launch_bounds__(256, 3) void gemm_f16(
    const u16* __restrict__ A, const u16* __restrict__ Bt,
    const float* __restrict__ bias, u16* __restrict__ C, int K, int N,
    int lognb, const float* __restrict__ rel, const float* __restrict__ w0tail) {
    __shared__ __align__(16) u16 As[2][128 * 64];
    __shared__ __align__(16) u16 Bs[128 * 64];
    const int tid = threadIdx.x;
    const int lane = tid & 63;
    const int wid = tid >> 6;
    const int r = lane & 15, q = lane >> 4;
    const int wm = (wid & 1) << 6, wn = (wid >> 1) << 6;

    const int g = blockIdx.x;
    const int n_idx = (g >> 3) & ((1 << lognb) - 1);
    const int m_idx = (g & 7) + ((g >> (3 + lognb)) << 3);
    const int n0 = n_idx << 7;
    const u32 m0 = (u32)m_idx << 7;

    const int srow = tid >> 3;
    const int schunk = (tid & 7) ^ (srow & 7);
    const u32 gaoff = (m0 + (u32)srow) * (u32)K + ((u32)schunk << 3);
    const u32 gboff = (u32)(n0 + srow) * (u32)K + ((u32)schunk << 3);

    auto stageA = [&](int kt, int buf) {
        const u16* gak = A + gaoff + (kt << 6);
        u16* la = &As[buf][tid * 8];
#pragma unroll
        for (int i = 0; i < 4; ++i)
            cp_async16(gak + (u32)(i << 5) * (u32)K, la + (i << 11));
    };

    u32x4 breg[4];
    auto loadB = [&](int kt) {
        const u16* gbk = Bt + gboff + (kt << 6);
#pragma unroll
        for (int i = 0; i < 4; ++i)
            breg[i] = *(const u32x4*)(gbk + (u32)(i << 5) * (u32)K);
    };
    auto writeB = [&]() {
        u16* lb = &Bs[tid * 8];
#pragma unroll
        for (int i = 0; i < 4; ++i)
            *(u32x4*)(lb + (i << 11)) = breg[i];
    };

    const int cx = (q ^ (r & 7)) << 3;
    const int arow = (wm + r) << 6, brow = (wn + r) << 6;

    floatx4 acc[4][4];
#pragma unroll
    for (int mi = 0; mi < 4; ++mi)
#pragma unroll
        for (int ni = 0; ni < 4; ++ni)
            acc[mi][ni] = (floatx4){0.0f, 0.0f, 0.0f, 0.0f};

    const int nk = K >> 6;
    loadB(0);
    stageA(0, 0);
    writeB();
    __syncthreads();

    for (int kt = 0; kt < nk; ++kt) {
        const int cur = kt & 1;
        const bool pf = (kt + 1 < nk);
        if (pf) {
            loadB(kt + 1);
            stageA(kt + 1, cur ^ 1);
        }
#pragma unroll
        for (int ks = 0; ks < 2; ++ks) {
            half8 af[4], bfr[4];
#pragma unroll
            for (int mi = 0; mi < 4; ++mi)
                af[mi] = *(const half8*)&As[cur][arow + (mi << 10) + (cx ^ (ks << 5))];
#pragma unroll
            for (int ni = 0; ni < 4; ++ni)
                bfr[ni] = *(const half8*)&Bs[brow + (ni << 10) + (cx ^ (ks << 5))];
#pragma unroll
            for (int mi = 0; mi < 4; ++mi)
#pragma unroll
                for (int ni = 0; ni < 4; ++ni)
                    acc[mi][ni] = __builtin_amdgcn_mfma_f32_16x16x32_f16(
                        af[mi], bfr[ni], acc[mi][ni], 0, 0, 0);
        }
        if (pf) {
            __syncthreads();
            writeB();
            __syncthreads();
        }
    }

    float bias_v[4], w0a[4], w0b[4];
#pragma unroll
    for (int ni = 0; ni < 4; ++ni) {
        int col = n0 + wn + ni * 16 + r;
        bias_v[ni] = bias[col];
        w0a[ni] = rel ? w0tail[col] : 0.0f;
        w0b[ni] = rel ? w0tail[N + col] : 0.0f;
    }
#pragma unroll
    for (int mi = 0; mi < 4; ++mi) {
#pragma unroll
        for (int rr = 0; rr < 4; ++rr) {
            u32 row = m0 + wm + mi * 16 + q * 4 + rr;
            float rl0 = 0.0f, rl1 = 0.0f;
            if (rel) {
                floatx2 rl = *(const floatx2*)&rel[(size_t)row * 2];
                rl0 = rl[0];
                rl1 = rl[1];
            }
            u32 pk[2];
#pragma unroll
            for (int h = 0; h < 2; ++h) {
                u32 w = 0;
#pragma unroll
                for (int j = 0; j < 2; ++j) {
                    int ni = h * 2 + j;
                    float v = acc[mi][ni][rr] + bias_v[ni];
                    if (rel) v += rl0 * w0a[ni] + rl1 * w0b[ni];
                    v = fmaxf(v, 0.0f);
                    w |= (u32)f2h(v) << (16 * j);
                }
                pk[h] = w;
            }
            *(u32x2*)(C + row * (u32)N + (u32)(n0 + wn + (r << 2))) =
                (u32x2){pk[0], pk[1]};
        }
    }
}

// ---------------- L4 (128 -> 2) + softmax combine ---------------------------
// one wave per point; A3 is packed-permuted -> index W4 through pi()
__global__ __launch_bounds__(256) void l4_combine(
    const u16* __restrict__ A3, const float* __restrict__ W4,
    const float* __restrict__ b4, float* __restrict__ out, int p0) {
    const int wid = threadIdx.x >> 6, lane = threadIdx.x & 63;
    const int pl = blockIdx.x * 4 + wid;
    const int p2 = lane * 2;
    const int s0 = p2 & 63, bb = p2 & ~63;
    const int k0 = bb + ((s0 & 3) << 4) + (s0 >> 2);
    const int s1 = s0 + 1;
    const int k1 = bb + ((s1 & 3) << 4) + (s1 >> 2);
    const float w00 = W4[k0 * 2], w01 = W4[k0 * 2 + 1];
    const float w10 = W4[k1 * 2], w11 = W4[k1 * 2 + 1];
    float P0[4], P1[4];
#pragma unroll
    for (int s = 0; s < 4; ++s) {
        size_t rowoff = ((size_t)pl * 4 + s) * 128 + p2;
        u32 av = *(const u32*)(A3 + rowoff);
        float a0 = h2f((u16)(av & 0xffffu));
        float a1 = h2f((u16)(av >> 16));
        float d0 = a0 * w00 + a1 * w10;
        float d1 = a0 * w01 + a1 * w11;
#pragma unroll
        for (int m = 32; m >= 1; m >>= 1) {
            d0 += __shfl_xor(d0, m, 64);
            d1 += __shfl_xor(d1, m, 64);
        }
        P0[s] = d0 + b4[0];
        P1[s] = d1 + b4[1];
    }
    if (lane == 0) {
        float mx = fmaxf(fmaxf(P1[0], P1[1]), fmaxf(P1[2], P1[3]));
        float e0 = __expf(P1[0] - mx), e1 = __expf(P1[1] - mx);
        float e2 = __expf(P1[2] - mx), e3 = __expf(P1[3] - mx);
        float se = e0 + e1 + e2 + e3;
        out[p0 + pl] = (P0[0] * e0 + P0[1] * e1 + P0[2] * e2 + P0[3] * e3) / se;
    }
}

// ---------------------------------------------------------------------------
extern "C" void kernel_launch(void* const* d_in, const int* in_sizes, int n_in,
                              void* d_out, int out_size, void* d_ws,
                              size_t ws_size, hipStream_t stream) {
    const float* feat = (const float*)d_in[0];
    const float* coord = (const float*)d_in[1];
    const float* hr = (const float*)d_in[2];
    const float* lr = (const float*)d_in[3];
    const float* W0 = (const float*)d_in[4];
    const float* b0 = (const float*)d_in[5];
    const float* W1 = (const float*)d_in[6];
    const float* b1 = (const float*)d_in[7];
    const float* W2 = (const float*)d_in[8];
    const float* b2 = (const float*)d_in[9];
    const float* W3 = (const float*)d_in[10];
    const float* b3 = (const float*)d_in[11];
    const float* W4 = (const float*)d_in[12];
    const float* b4 = (const float*)d_in[13];
    float* out = (float*)d_out;

    char* base = (char*)d_ws;
    size_t off = 0;
    auto carve = [&](size_t bytes) -> char* {
        char* p = base + off;
        off += (bytes + 255) & ~(size_t)255;
        return p;
    };

    u16* hrT = (u16*)carve(4ull * 65536 * 128 * 2);   // [4][256][256][128] f16
    u16* featT = (u16*)carve(4ull * 4096 * 128 * 2);  // [4][64][64][128] f16
    u16* lrT = (u16*)carve(4ull * 4096 * 128 * 2);
    u16* Wt0 = (u16*)carve(1024ull * 384 * 2);        // [N][K] f16
    u16* Wt1 = (u16*)carve(512ull * 1024 * 2);
    u16* Wt2 = (u16*)carve(256ull * 512 * 2);
    u16* Wt3 = (u16*)carve(128ull * 256 * 2);
    const size_t fixed = off;

    const size_t R = 1048576ull;  // 262144 points * 4 shifts
    // c = 16 minimum: chunk working set (X 50MB + A0 134MB) stays inside the
    // 256MB L3 so inter-layer activations never round-trip HBM.
    int c = 16;
    for (; c < 8192; c *= 2) {
        size_t Rc = R / c;
        size_t need = fixed;
        size_t sizes[3] = {Rc * 1024, Rc * 8, Rc * 2048};
        for (int i = 0; i < 3; ++i) need += (sizes[i] + 255) & ~(size_t)255;
        if (need <= ws_size) break;
    }
    const size_t Rc = R / c;
    const int Pc = (int)(262144 / c);

    char* R1 = carve(Rc * 1024);
    float* rel = (float*)carve(Rc * 8);
    char* R2 = carve(Rc * 2048);
    u16* X = (u16*)R1;                   // [Rc][384] f16 (dead after L0)
    u16* A1 = (u16*)R1;                  // [Rc][512]  (overwrites X in L1)
    u16* A0 = (u16*)R2;                  // [Rc][1024] (dead after L1)
    u16* A2 = (u16*)R2;                  // [Rc][256]  (overwrites A0 in L2)
    u16* A3 = (u16*)(R2 + Rc * 512);     // [Rc][128]  (disjoint from A2)

    transpose_chw_hwc<<<dim3(2048, 4, 4), dim3(32, 8), 0, stream>>>(hr, hrT, 65536);
    transpose_chw_hwc<<<dim3(128, 4, 4), dim3(32, 8), 0, stream>>>(feat, featT, 4096);
    transpose_chw_hwc<<<dim3(128, 4, 4), dim3(32, 8), 0, stream>>>(lr, lrT, 4096);
    prep_wt<<<(1024 * 384 + 255) / 256, 256, 0, stream>>>(W0, Wt0, 384, 1024, 0);
    prep_wt<<<(512 * 1024 + 255) / 256, 256, 0, stream>>>(W1, Wt1, 1024, 512, 1);
    prep_wt<<<(256 * 512 + 255) / 256, 256, 0, stream>>>(W2, Wt2, 512, 256, 1);
    prep_wt<<<(128 * 256 + 255) / 256, 256, 0, stream>>>(W3, Wt3, 256, 128, 1);

    const int mt1 = (int)(Rc / 128);  // 128-row tiles (128x128 kernel)
    const int mt2 = (int)(Rc / 256);  // 256-row tiles (8-phase kernel)
    const bool use256 = (Rc % 2048ull) == 0;  // mt2 multiple of 8
    for (int ci = 0; ci < c; ++ci) {
        const int p0 = ci * Pc;
        gather_build<<<Pc / 4, 256, 0, stream>>>(coord, hrT, featT, lrT, X, rel, p0);
        // L0 (nk=6, short K): 128x128 kernel, 3 blocks/CU hides ramp/drain.
        gemm_f16<<<mt1 * 8, 256, 0, stream>>>(X, Wt0, b0, A0, 384, 1024, 3, rel,
                                              W0 + 384 * 1024);
        if (use256) {
            // L1 (nk=16) / L2 (nk=8): deep-pipelined 256x256 kernel.
            gemm_f16_256<<<mt2 * 2, 512, 0, stream>>>(A0, Wt1, b1, A1, 1024, 512,
                                                      1, nullptr, nullptr);
            gemm_f16_256<<<mt2 * 1, 512, 0, stream>>>(A1, Wt2, b2, A2, 512, 256,
                                                      0, nullptr, nullptr);
        } else {
            gemm_f16<<<mt1 * 4, 256, 0, stream>>>(A0, Wt1, b1, A1, 1024, 512, 2,
                                                  nullptr, nullptr);
            gemm_f16<<<mt1 * 2, 256, 0, stream>>>(A1, Wt2, b2, A2, 512, 256, 1,
                                                  nullptr, nullptr);
        }
        gemm_f16<<<mt1 * 1, 256, 0, stream>>>(A2, Wt3, b3, A3, 256, 128, 0,
                                              nullptr, nullptr);
        l4_combine<<<Pc / 4, 256, 0, stream>>>(A3, W4, b4, out, p0);
    }
}

// Round 5
// 3403.577 us; speedup vs baseline: 1.5614x; 1.0924x over previous
//
#include <hip/hip_runtime.h>
#include <cstdint>
#include <cstddef>

// ---------------------------------------------------------------------------
// JIIF fused pipeline (round 11 = round 10 + algebraic L0 split + L3/L4 fuse):
//   - L0 factorization: X@W0 = qf@W0a + qhr@(W0b+W0c) - qlr@W0c.
//     h = qhr@(W0b+W0c) + b0 computed ONCE PER POINT (K=128 GEMM, 1/12 of
//     L0 FLOPs); main L0 GEMM shrinks to K=256 (nk 6->4, -33% K-loop).
//     h stored packed-permuted f16; L0 epilogue reads it as its "bias".
//     gather no longer computes/stores the hr-lr diff block (-25% X bytes).
//   - L3+L4 fused: L3 block (lognb=0) owns all 128 cols of its 128 rows and
//     each lane's rr-range is one point's 4 shifts -> relu+bias, 4-col W4
//     dot, 16-lane shuffle reduce, 2KB LDS cross-wave combine, softmax,
//     write out[] directly.  A3 buffer + l4_combine kernel deleted.
//   - memory: Qhr aliases R2 (dead before A0 written); H = R1 second half
//     (X shrank to Rc*512 B); zero extra workspace.
//   - routing/chunking unchanged: L0/h/L3 on 128x128 kernel (3 blocks/CU),
//     L1/L2 on 256x256 8-phase kernel, c=16 L3-resident chunks.
// Rows ordered point-major: row = point*4 + shift.
// ---------------------------------------------------------------------------

typedef unsigned short u16;
typedef unsigned int u32;
typedef _Float16 half8 __attribute__((ext_vector_type(8)));
typedef float floatx4 __attribute__((ext_vector_type(4)));
typedef float floatx2 __attribute__((ext_vector_type(2)));
typedef u32 u32x2 __attribute__((ext_vector_type(2)));
typedef u32 u32x4 __attribute__((ext_vector_type(4)));

__device__ __forceinline__ u16 f2h(float x) {
    _Float16 h = (_Float16)x;
    return __builtin_bit_cast(unsigned short, h);
}
__device__ __forceinline__ float h2f(u16 u) {
    return (float)__builtin_bit_cast(_Float16, u);
}

// async 16B global -> LDS (wave-uniform LDS base + lane*16)
__device__ __forceinline__ void cp_async16(const void* gsrc, void* lds) {
#if defined(__has_builtin) && __has_builtin(__builtin_amdgcn_global_load_lds)
    __builtin_amdgcn_global_load_lds(
        (__attribute__((address_space(1))) void*)(uintptr_t)gsrc,
        (__attribute__((address_space(3))) void*)(uint32_t)(uintptr_t)lds,
        16, 0, 0);
#else
    *(u32x4*)lds = *(const u32x4*)gsrc;
#endif
}

// ---------------- transpose [B][C=128][HW] fp32 -> [B][HW][C] fp16 ----------
__global__ void transpose_chw_hwc(const float* __restrict__ src,
                                  u16* __restrict__ dst, int HW) {
    __shared__ float t[32][33];
    const int b = blockIdx.z;
    const int hw0 = blockIdx.x * 32, c0 = blockIdx.y * 32;
    const float* s = src + (size_t)b * 128 * HW;
    u16* d = dst + (size_t)b * HW * 128;
    const int tx = threadIdx.x, ty = threadIdx.y;
#pragma unroll
    for (int j = 0; j < 4; ++j)
        t[ty + j * 8][tx] = s[(size_t)(c0 + ty + j * 8) * HW + hw0 + tx];
    __syncthreads();
#pragma unroll
    for (int j = 0; j < 4; ++j)
        d[(size_t)(hw0 + ty + j * 8) * 128 + c0 + tx] = f2h(t[tx][ty + j * 8]);
}

// ---------------- weight transpose: W [K x N] fp32 -> Wt [N x K] fp16 -------
// perm!=0: stored k index kk holds source channel
//   pi(kk) = (kk & ~63) + (kk&3)*16 + ((kk>>2)&15)   (matches packed C store)
__global__ void prep_wt(const float* __restrict__ W, u16* __restrict__ Wt,
                        int K, int N, int perm) {
    int idx = blockIdx.x * 256 + threadIdx.x;
    if (idx >= N * K) return;
    int nn = idx / K, kk = idx - nn * K;
    int ka = kk;
    if (perm) {
        int s = kk & 63;
        ka = (kk & ~63) + ((s & 3) << 4) + (s >> 2);
    }
    Wt[idx] = f2h(W[(size_t)ka * N + nn]);
}

// ---------------- W0 split prep ---------------------------------------------
// W0 rows: 0-127 q_feat (W0a), 128-255 q_hr (W0b), 256-383 diff (W0c).
// Wt0m [1024][256]: k<128 -> W0a[k]; k>=128 -> -W0c[k-128]  (X = [qf | qlr])
// Wthr [1024][128]: W0b[k] + W0c[k]                          (h-GEMM weights)
__global__ void prep_w0(const float* __restrict__ W0, u16* __restrict__ Wt0m,
                        u16* __restrict__ Wthr) {
    int idx = blockIdx.x * 256 + threadIdx.x;
    if (idx < 1024 * 256) {
        int n = idx >> 8, k = idx & 255;
        float v = (k < 128) ? W0[(size_t)k * 1024 + n]
                            : -W0[(size_t)(128 + k) * 1024 + n];
        Wt0m[idx] = f2h(v);
    }
    if (idx < 1024 * 128) {
        int n = idx >> 7, k = idx & 127;
        Wthr[idx] = f2h(W0[(size_t)(128 + k) * 1024 + n] +
                        W0[(size_t)(256 + k) * 1024 + n]);
    }
}

// ---------------- gather / build X + Qhr ------------------------------------
// one wave per point (4 waves/block); lane handles channel pair (2l, 2l+1)
// X rows: [q_feat(128) | q_lr(128)]; Qhr: [point][128] natural order.
__global__ __launch_bounds__(256) void gather_build(
    const float* __restrict__ coord, const u16* __restrict__ hrT,
    const u16* __restrict__ featT, const u16* __restrict__ lrT,
    u16* __restrict__ X, u16* __restrict__ Qhr, float* __restrict__ rel,
    int p0) {
    const int wid = threadIdx.x >> 6, lane = threadIdx.x & 63;
    const int pl = blockIdx.x * 4 + wid;
    const int p = p0 + pl;
    const int b = p >> 16;  // N per batch = 65536
    const float cy = coord[(size_t)p * 2];
    const float cx = coord[(size_t)p * 2 + 1];
    const u32* hr32 = (const u32*)hrT;
    const u32* ft32 = (const u32*)featT;
    const u32* lr32 = (const u32*)lrT;

    // hr sample at unshifted coord (H=W=256)
    float fy = rintf(((cy + 1.0f) * 256.0f - 1.0f) * 0.5f);
    float fx = rintf(((cx + 1.0f) * 256.0f - 1.0f) * 0.5f);
    bool vh = (fy >= 0.0f) && (fy < 256.0f) && (fx >= 0.0f) && (fx < 256.0f);
    int iy = (int)fminf(fmaxf(fy, 0.0f), 255.0f);
    int ix = (int)fminf(fmaxf(fx, 0.0f), 255.0f);
    u32 hrv = hr32[((((size_t)b * 256 + iy) * 256 + ix) * 128 >> 1) + lane];
    if (!vh) hrv = 0u;
    ((u32*)Qhr)[(size_t)pl * 64 + lane] = hrv;

    const size_t rowbase = (size_t)pl * 4;
#pragma unroll
    for (int s = 0; s < 4; ++s) {
        // shift order: s=0:(-1,-1) 1:(-1,+1) 2:(+1,-1) 3:(+1,+1) over (vx,vy)
        float sy = (s & 2) ? 0.015625f : -0.015625f;
        float sx = (s & 1) ? 0.015625f : -0.015625f;
        float gy = rintf(((cy + sy + 1.0f) * 64.0f - 1.0f) * 0.5f);
        float gx = rintf(((cx + sx + 1.0f) * 64.0f - 1.0f) * 0.5f);
        bool v = (gy >= 0.0f) && (gy < 64.0f) && (gx >= 0.0f) && (gx < 64.0f);
        int jy = (int)fminf(fmaxf(gy, 0.0f), 63.0f);
        int jx = (int)fminf(fmaxf(gx, 0.0f), 63.0f);
        size_t g32 = ((((size_t)b * 64 + jy) * 64 + jx) * 128 >> 1) + lane;
        u32 fv = ft32[g32];
        u32 lv = lr32[g32];
        if (!v) { fv = 0u; lv = 0u; }

        u32* xr = (u32*)(X + (rowbase + s) * 256);
        xr[lane] = fv;        // q_feat
        xr[64 + lane] = lv;   // q_lr (weights hold the -W0c sign)

        if (lane == 0) {
            float qcy = v ? (-0.984375f + 0.03125f * (float)jy) : 0.0f;
            float qcx = v ? (-0.984375f + 0.03125f * (float)jx) : 0.0f;
            rel[(rowbase + s) * 2 + 0] = (cy - qcy) * 64.0f;
            rel[(rowbase + s) * 2 + 1] = (cx - qcx) * 64.0f;
        }
    }
}

// ---------------- 256x256-tile 8-phase GEMM + bias + ReLU (long K) ----------
__global__ __launch_bounds__(512, 2) void gemm_f16_256(
    const u16* __restrict__ A, const u16* __restrict__ Bt,
    const float* __restrict__ bias, u16* __restrict__ C, int K, int N,
    int lognb, const float* __restrict__ rel, const float* __restrict__ w0tail) {
    __shared__ __align__(16) u16 sA[2][2][8192];  // [buf][ks][256*32]
    __shared__ __align__(16) u16 sB[2][2][8192];
    const int tid = threadIdx.x;
    const int lane = tid & 63;
    const int wid = tid >> 6;
    const int r = lane & 15, q = lane >> 4;
    const int wm = wid >> 2, wn = wid & 3;

    const int g = blockIdx.x;
    const int n_idx = (g >> 3) & ((1 << lognb) - 1);
    const int m_idx = (g & 7) + ((g >> (3 + lognb)) << 3);
    const int n0 = n_idx << 8;
    const u32 m0 = (u32)m_idx << 8;

    const u32 srow = (u32)(tid >> 2);
    const u32 gchunk = (u32)((tid & 3) ^ ((tid >> 3) & 3));
    const u32 gaoff = (m0 + srow) * (u32)K + (gchunk << 3);
    const u32 gboff = ((u32)n0 + srow) * (u32)K + (gchunk << 3);

    auto stageA = [&](int kt, int ks, int buf) {
        const u16* gp = A + gaoff + (u32)((kt << 6) + (ks << 5));
        u16* lp = &sA[buf][ks][tid << 3];
        cp_async16(gp, lp);
        cp_async16(gp + ((u32)K << 7), lp + 4096);
    };
    auto stageB = [&](int kt, int ks, int buf) {
        const u16* gp = Bt + gboff + (u32)((kt << 6) + (ks << 5));
        u16* lp = &sB[buf][ks][tid << 3];
        cp_async16(gp, lp);
        cp_async16(gp + ((u32)K << 7), lp + 4096);
    };

    const int fs = (q ^ ((r >> 1) & 3)) << 3;
    const int abase = ((wm << 7) + r) * 32 + fs;  // + mi*512
    const int bbase = ((wn << 6) + r) * 32 + fs;  // + nh*1024 + ni*512

    floatx4 acc[8][4];
#pragma unroll
    for (int mi = 0; mi < 8; ++mi)
#pragma unroll
        for (int ni = 0; ni < 4; ++ni)
            acc[mi][ni] = (floatx4){0.0f, 0.0f, 0.0f, 0.0f};

    const int nk = K >> 6;
    stageA(0, 0, 0);
    stageA(0, 1, 0);
    stageB(0, 0, 0);
    stageB(0, 1, 0);
    const int k1 = (nk > 1) ? 1 : 0;
    stageA(k1, 0, 1);
    stageA(k1, 1, 1);
    stageB(k1, 1, 1);
    asm volatile("s_waitcnt vmcnt(6)");
    __builtin_amdgcn_s_barrier();

    for (int kt = 0; kt < nk; ++kt) {
        const int cur = kt & 1, nxt = cur ^ 1;
        const bool p1 = (kt + 1) < nk;
        const bool p2 = (kt + 2) < nk;
        half8 a0[8], a1[8], bf[2];
        // ---- phase 1
#pragma unroll
        for (int mi = 0; mi < 8; ++mi)
            a0[mi] = *(const half8*)&sA[cur][0][abase + (mi << 9)];
#pragma unroll
        for (int ni = 0; ni < 2; ++ni)
            bf[ni] = *(const half8*)&sB[cur][0][bbase + (ni << 9)];
        if (p1) stageB(kt + 1, 0, nxt);
        __builtin_amdgcn_s_barrier();
        asm volatile("s_waitcnt lgkmcnt(0)");
        __builtin_amdgcn_s_setprio(1);
#pragma unroll
        for (int mi = 0; mi < 8; ++mi)
#pragma unroll
            for (int ni = 0; ni < 2; ++ni)
                acc[mi][ni] = __builtin_amdgcn_mfma_f32_16x16x32_f16(
                    a0[mi], bf[ni], acc[mi][ni], 0, 0, 0);
        __builtin_amdgcn_s_setprio(0);
        __builtin_amdgcn_s_barrier();
        // ---- phase 2
#pragma unroll
        for (int mi = 0; mi < 8; ++mi)
            a1[mi] = *(const half8*)&sA[cur][1][abase + (mi << 9)];
#pragma unroll
        for (int ni = 0; ni < 2; ++ni)
            bf[ni] = *(const half8*)&sB[cur][1][bbase + (ni << 9)];
        if (p2) stageA(kt + 2, 0, cur);
        __builtin_amdgcn_s_barrier();
        asm volatile("s_waitcnt lgkmcnt(0)");
        __builtin_amdgcn_s_setprio(1);
#pragma unroll
        for (int mi = 0; mi < 8; ++mi)
#pragma unroll
            for (int ni = 0; ni < 2; ++ni)
                acc[mi][ni] = __builtin_amdgcn_mfma_f32_16x16x32_f16(
                    a1[mi], bf[ni], acc[mi][ni], 0, 0, 0);
        __builtin_amdgcn_s_setprio(0);
        __builtin_amdgcn_s_barrier();
        // ---- phase 3
#pragma unroll
        for (int ni = 0; ni < 2; ++ni)
            bf[ni] = *(const half8*)&sB[cur][1][bbase + 1024 + (ni << 9)];
        if (p2) stageA(kt + 2, 1, cur);
        __builtin_amdgcn_s_barrier();
        asm volatile("s_waitcnt lgkmcnt(0)");
        __builtin_amdgcn_s_setprio(1);
#pragma unroll
        for (int mi = 0; mi < 8; ++mi)
#pragma unroll
            for (int ni = 0; ni < 2; ++ni)
                acc[mi][2 + ni] = __builtin_amdgcn_mfma_f32_16x16x32_f16(
                    a1[mi], bf[ni], acc[mi][2 + ni], 0, 0, 0);
        __builtin_amdgcn_s_setprio(0);
        __builtin_amdgcn_s_barrier();
        // ---- phase 4
#pragma unroll
        for (int ni = 0; ni < 2; ++ni)
            bf[ni] = *(const half8*)&sB[cur][0][bbase + 1024 + (ni << 9)];
        if (p2) stageB(kt + 2, 1, cur);
        __builtin_amdgcn_s_barrier();
        asm volatile("s_waitcnt lgkmcnt(0)");
        __builtin_amdgcn_s_setprio(1);
#pragma unroll
        for (int mi = 0; mi < 8; ++mi)
#pragma unroll
            for (int ni = 0; ni < 2; ++ni)
                acc[mi][2 + ni] = __builtin_amdgcn_mfma_f32_16x16x32_f16(
                    a0[mi], bf[ni], acc[mi][2 + ni], 0, 0, 0);
        __builtin_amdgcn_s_setprio(0);
        if (p2) {
            asm volatile("s_waitcnt vmcnt(6)");
        } else {
            asm volatile("s_waitcnt vmcnt(0)");
        }
        __builtin_amdgcn_s_barrier();
    }

    float bias_v[4], w0a[4], w0b[4];
#pragma unroll
    for (int nig = 0; nig < 4; ++nig) {
        int col = n0 + (wn << 6) + nig * 16 + r;
        bias_v[nig] = bias[col];
        w0a[nig] = rel ? w0tail[col] : 0.0f;
        w0b[nig] = rel ? w0tail[N + col] : 0.0f;
    }
#pragma unroll
    for (int mi = 0; mi < 8; ++mi) {
#pragma unroll
        for (int rr = 0; rr < 4; ++rr) {
            u32 row = m0 + (u32)(wm << 7) + (u32)(mi << 4) + (u32)(q << 2) +
                      (u32)rr;
            float rl0 = 0.0f, rl1 = 0.0f;
            if (rel) {
                floatx2 rl = *(const floatx2*)&rel[(size_t)row * 2];
                rl0 = rl[0];
                rl1 = rl[1];
            }
            u32 pk[2];
#pragma unroll
            for (int h = 0; h < 2; ++h) {
                u32 w = 0;
#pragma unroll
                for (int j = 0; j < 2; ++j) {
                    int nig = h * 2 + j;
                    float v = acc[mi][nig][rr] + bias_v[nig];
                    if (rel) v += rl0 * w0a[nig] + rl1 * w0b[nig];
                    v = fmaxf(v, 0.0f);
                    w |= (u32)f2h(v) << (16 * j);
                }
                pk[h] = w;
            }
            *(u32x2*)(C + row * (u32)N + (u32)(n0 + (wn << 6) + (r << 2))) =
                (u32x2){pk[0], pk[1]};
        }
    }
}

// ---------------- 128x128 GEMM (short-K layers: h, L0) ----------------------
// hq != nullptr: per-point packed-permuted f16 row H[row>>2][N] replaces bias
// (bias may be null).  doRelu: apply ReLU (off for the h partial-sum GEMM).
__global__ __launch_bounds__(256, 3) void gemm_f16(
    const u16* __restrict__ A, const u16* __restrict__ Bt,
    const float* __restrict__ bias, u16* __restrict__ C, int K, int N,
    int lognb, const float* __restrict__ rel, const float* __restrict__ w0tail,
    const u16* __restrict__ hq, int doRelu) {
    __shared__ __align__(16) u16 As[2][128 * 64];
    __shared__ __align__(16) u16 Bs[128 * 64];
    const int tid = threadIdx.x;
    const int lane = tid & 63;
    const int wid = tid >> 6;
    const int r = lane & 15, q = lane >> 4;
    const int wm = (wid & 1) << 6, wn = (wid >> 1) << 6;

    const int g = blockIdx.x;
    const int n_idx = (g >> 3) & ((1 << lognb) - 1);
    const int m_idx = (g & 7) + ((g >> (3 + lognb)) << 3);
    const int n0 = n_idx << 7;
    const u32 m0 = (u32)m_idx << 7;

    const int srow = tid >> 3;
    const int schunk = (tid & 7) ^ (srow & 7);
    const u32 gaoff = (m0 + (u32)srow) * (u32)K + ((u32)schunk << 3);
    const u32 gboff = (u32)(n0 + srow) * (u32)K + ((u32)schunk << 3);

    auto stageA = [&](int kt, int buf) {
        const u16* gak = A + gaoff + (kt << 6);
        u16* la = &As[buf][tid * 8];
#pragma unroll
        for (int i = 0; i < 4; ++i)
            cp_async16(gak + (u32)(i << 5) * (u32)K, la + (i << 11));
    };

    u32x4 breg[4];
    auto loadB = [&](int kt) {
        const u16* gbk = Bt + gboff + (kt << 6);
#pragma unroll
        for (int i = 0; i < 4; ++i)
            breg[i] = *(const u32x4*)(gbk + (u32)(i << 5) * (u32)K);
    };
    auto writeB = [&]() {
        u16* lb = &Bs[tid * 8];
#pragma unroll
        for (int i = 0; i < 4; ++i)
            *(u32x4*)(lb + (i << 11)) = breg[i];
    };

    const int cx = (q ^ (r & 7)) << 3;
    const int arow = (wm + r) << 6, brow = (wn + r) << 6;

    floatx4 acc[4][4];
#pragma unroll
    for (int mi = 0; mi < 4; ++mi)
#pragma unroll
        for (int ni = 0; ni < 4; ++ni)
            acc[mi][ni] = (floatx4){0.0f, 0.0f, 0.0f, 0.0f};

    const int nk = K >> 6;
    loadB(0);
    stageA(0, 0);
    writeB();
    __syncthreads();

    for (int kt = 0; kt < nk; ++kt) {
        const int cur = kt & 1;
        const bool pf = (kt + 1 < nk);
        if (pf) {
            loadB(kt + 1);
            stageA(kt + 1, cur ^ 1);
        }
#pragma unroll
        for (int ks = 0; ks < 2; ++ks) {
            half8 af[4], bfr[4];
#pragma unroll
            for (int mi = 0; mi < 4; ++mi)
                af[mi] = *(const half8*)&As[cur][arow + (mi << 10) + (cx ^ (ks << 5))];
#pragma unroll
            for (int ni = 0; ni < 4; ++ni)
                bfr[ni] = *(const half8*)&Bs[brow + (ni << 10) + (cx ^ (ks << 5))];
#pragma unroll
            for (int mi = 0; mi < 4; ++mi)
#pragma unroll
                for (int ni = 0; ni < 4; ++ni)
                    acc[mi][ni] = __builtin_amdgcn_mfma_f32_16x16x32_f16(
                        af[mi], bfr[ni], acc[mi][ni], 0, 0, 0);
        }
        if (pf) {
            __syncthreads();
            writeB();
            __syncthreads();
        }
    }

    float bias_v[4], w0a[4], w0b[4];
#pragma unroll
    for (int ni = 0; ni < 4; ++ni) {
        int col = n0 + wn + ni * 16 + r;
        bias_v[ni] = bias ? bias[col] : 0.0f;
        w0a[ni] = rel ? w0tail[col] : 0.0f;
        w0b[ni] = rel ? w0tail[N + col] : 0.0f;
    }
#pragma unroll
    for (int mi = 0; mi < 4; ++mi) {
        float addv[4];
        if (hq) {
            u32 pidx = ((m0 + (u32)wm + (u32)(mi << 4)) >> 2) + (u32)q;
            u32x2 hv = *(const u32x2*)(hq + (size_t)pidx * (u32)N +
                                       (u32)(n0 + wn + (r << 2)));
            addv[0] = h2f((u16)(hv[0] & 0xffffu));
            addv[1] = h2f((u16)(hv[0] >> 16));
            addv[2] = h2f((u16)(hv[1] & 0xffffu));
            addv[3] = h2f((u16)(hv[1] >> 16));
        } else {
#pragma unroll
            for (int ni = 0; ni < 4; ++ni) addv[ni] = bias_v[ni];
        }
#pragma unroll
        for (int rr = 0; rr < 4; ++rr) {
            u32 row = m0 + wm + mi * 16 + q * 4 + rr;
            float rl0 = 0.0f, rl1 = 0.0f;
            if (rel) {
                floatx2 rl = *(const floatx2*)&rel[(size_t)row * 2];
                rl0 = rl[0];
                rl1 = rl[1];
            }
            u32 pk[2];
#pragma unroll
            for (int h = 0; h < 2; ++h) {
                u32 w = 0;
#pragma unroll
                for (int j = 0; j < 2; ++j) {
                    int ni = h * 2 + j;
                    float v = acc[mi][ni][rr] + addv[ni];
                    if (rel) v += rl0 * w0a[ni] + rl1 * w0b[ni];
                    if (doRelu) v = fmaxf(v, 0.0f);
                    w |= (u32)f2h(v) << (16 * j);
                }
                pk[h] = w;
            }
            *(u32x2*)(C + row * (u32)N + (u32)(n0 + wn + (r << 2))) =
                (u32x2){pk[0], pk[1]};
        }
    }
}

// ---------------- fused L3 GEMM + L4 + softmax combine ----------------------
// K=256, N=128, one block per 128 rows (32 points); grid = M/128.
// Epilogue: relu(C+b3) -> per-lane 4-col W4 dot -> 16-lane shuffle reduce ->
// LDS cross-wave combine -> lane-local softmax over the 4 shifts -> out.
__global__ __launch_bounds__(256, 3) void gemm_l3l4(
    const u16* __restrict__ A, const u16* __restrict__ Bt,
    const float* __restrict__ b3, const float* __restrict__ W4,
    const float* __restrict__ b4, float* __restrict__ out, int p0) {
    __shared__ __align__(16) u16 As[2][128 * 64];
    __shared__ __align__(16) u16 Bs[128 * 64];
    __shared__ float sums[2][2][64][2];
    const int K = 256;
    const int tid = threadIdx.x;
    const int lane = tid & 63;
    const int wid = tid >> 6;
    const int r = lane & 15, q = lane >> 4;
    const int wm1 = wid & 1, wn1 = wid >> 1;
    const int wm = wm1 << 6, wn = wn1 << 6;
    const u32 m0 = (u32)blockIdx.x << 7;

    const int srow = tid >> 3;
    const int schunk = (tid & 7) ^ (srow & 7);
    const u32 gaoff = (m0 + (u32)srow) * (u32)K + ((u32)schunk << 3);
    const u32 gboff = (u32)srow * (u32)K + ((u32)schunk << 3);

    auto stageA = [&](int kt, int buf) {
        const u16* gak = A + gaoff + (kt << 6);
        u16* la = &As[buf][tid * 8];
#pragma unroll
        for (int i = 0; i < 4; ++i)
            cp_async16(gak + (u32)(i << 5) * (u32)K, la + (i << 11));
    };

    u32x4 breg[4];
    auto loadB = [&](int kt) {
        const u16* gbk = Bt + gboff + (kt << 6);
#pragma unroll
        for (int i = 0; i < 4; ++i)
            breg[i] = *(const u32x4*)(gbk + (u32)(i << 5) * (u32)K);
    };
    auto writeB = [&]() {
        u16* lb = &Bs[tid * 8];
#pragma unroll
        for (int i = 0; i < 4; ++i)
            *(u32x4*)(lb + (i << 11)) = breg[i];
    };

    const int cx = (q ^ (r & 7)) << 3;
    const int arow = (wm + r) << 6, brow = (wn + r) << 6;

    floatx4 acc[4][4];
#pragma unroll
    for (int mi = 0; mi < 4; ++mi)
#pragma unroll
        for (int ni = 0; ni < 4; ++ni)
            acc[mi][ni] = (floatx4){0.0f, 0.0f, 0.0f, 0.0f};

    const int nk = K >> 6;  // 4
    loadB(0);
    stageA(0, 0);
    writeB();
    __syncthreads();
    for (int kt = 0; kt < nk; ++kt) {
        const int cur = kt & 1;
        const bool pf = (kt + 1 < nk);
        if (pf) {
            loadB(kt + 1);
            stageA(kt + 1, cur ^ 1);
        }
#pragma unroll
        for (int ks = 0; ks < 2; ++ks) {
            half8 af[4], bfr[4];
#pragma unroll
            for (int mi = 0; mi < 4; ++mi)
                af[mi] = *(const half8*)&As[cur][arow + (mi << 10) + (cx ^ (ks << 5))];
#pragma unroll
            for (int ni = 0; ni < 4; ++ni)
                bfr[ni] = *(const half8*)&Bs[brow + (ni << 10) + (cx ^ (ks << 5))];
#pragma unroll
            for (int mi = 0; mi < 4; ++mi)
#pragma unroll
                for (int ni = 0; ni < 4; ++ni)
                    acc[mi][ni] = __builtin_amdgcn_mfma_f32_16x16x32_f16(
                        af[mi], bfr[ni], acc[mi][ni], 0, 0, 0);
        }
        if (pf) {
            __syncthreads();
            writeB();
            __syncthreads();
        }
    }

    // ---- fused L4: channel ch = wn + ni*16 + r (natural index) ----
    float b3v[4], w40[4], w41[4];
#pragma unroll
    for (int ni = 0; ni < 4; ++ni) {
        int ch = wn + ni * 16 + r;
        b3v[ni] = b3[ch];
        w40[ni] = W4[ch * 2];
        w41[ni] = W4[ch * 2 + 1];
    }
#pragma unroll
    for (int mi = 0; mi < 4; ++mi) {
#pragma unroll
        for (int rr = 0; rr < 4; ++rr) {
            float d0 = 0.0f, d1 = 0.0f;
#pragma unroll
            for (int ni = 0; ni < 4; ++ni) {
                float v = fmaxf(acc[mi][ni][rr] + b3v[ni], 0.0f);
                d0 += v * w40[ni];
                d1 += v * w41[ni];
            }
#pragma unroll
            for (int m = 1; m <= 8; m <<= 1) {
                d0 += __shfl_xor(d0, m, 64);
                d1 += __shfl_xor(d1, m, 64);
            }
            if (r == 0) {
                int rl = mi * 16 + q * 4 + rr;
                sums[wm1][wn1][rl][0] = d0;
                sums[wm1][wn1][rl][1] = d1;
            }
        }
    }
    __syncthreads();
    if (tid < 32) {
        const int pl = tid;
        const int w = pl >> 4;
        const int rb = (pl & 15) * 4;
        float P0[4], P1[4];
#pragma unroll
        for (int s = 0; s < 4; ++s) {
            P0[s] = sums[w][0][rb + s][0] + sums[w][1][rb + s][0] + b4[0];
            P1[s] = sums[w][0][rb + s][1] + sums[w][1][rb + s][1] + b4[1];
        }
        float mx = fmaxf(fmaxf(P1[0], P1[1]), fmaxf(P1[2], P1[3]));
        float e0 = __expf(P1[0] - mx), e1 = __expf(P1[1] - mx);
        float e2 = __expf(P1[2] - mx), e3 = __expf(P1[3] - mx);
        float se = e0 + e1 + e2 + e3;
        out[p0 + (int)(m0 >> 2) + pl] =
            (P0[0] * e0 + P0[1] * e1 + P0[2] * e2 + P0[3] * e3) / se;
    }
}

// ---------------------------------------------------------------------------
extern "C" void kernel_launch(void* const* d_in, const int* in_sizes, int n_in,
                              void* d_out, int out_size, void* d_ws,
                              size_t ws_size, hipStream_t stream) {
    const float* feat = (const float*)d_in[0];
    const float* coord = (const float*)d_in[1];
    const float* hr = (const float*)d_in[2];
    const float* lr = (const float*)d_in[3];
    const float* W0 = (const float*)d_in[4];
    const float* b0 = (const float*)d_in[5];
    const float* W1 = (const float*)d_in[6];
    const float* b1 = (const float*)d_in[7];
    const float* W2 = (const float*)d_in[8];
    const float* b2 = (const float*)d_in[9];
    const float* W3 = (const float*)d_in[10];
    const float* b3 = (const float*)d_in[11];
    const float* W4 = (const float*)d_in[12];
    const float* b4 = (const float*)d_in[13];
    float* out = (float*)d_out;

    char* base = (char*)d_ws;
    size_t off = 0;
    auto carve = [&](size_t bytes) -> char* {
        char* p = base + off;
        off += (bytes + 255) & ~(size_t)255;
        return p;
    };

    u16* hrT = (u16*)carve(4ull * 65536 * 128 * 2);   // [4][256][256][128] f16
    u16* featT = (u16*)carve(4ull * 4096 * 128 * 2);  // [4][64][64][128] f16
    u16* lrT = (u16*)carve(4ull * 4096 * 128 * 2);
    u16* Wt0m = (u16*)carve(1024ull * 256 * 2);       // [N][256] qf|-qlr
    u16* Wthr = (u16*)carve(1024ull * 128 * 2);       // [N][128] W0b+W0c
    u16* Wt1 = (u16*)carve(512ull * 1024 * 2);
    u16* Wt2 = (u16*)carve(256ull * 512 * 2);
    u16* Wt3 = (u16*)carve(128ull * 256 * 2);
    const size_t fixed = off;

    const size_t R = 1048576ull;  // 262144 points * 4 shifts
    // c = 16 minimum: chunk working set stays inside the 256MB L3.
    int c = 16;
    for (; c < 8192; c *= 2) {
        size_t Rc = R / c;
        size_t need = fixed;
        size_t sizes[3] = {Rc * 1024, Rc * 8, Rc * 2048};
        for (int i = 0; i < 3; ++i) need += (sizes[i] + 255) & ~(size_t)255;
        if (need <= ws_size) break;
    }
    const size_t Rc = R / c;
    const int Pc = (int)(262144 / c);

    char* R1 = carve(Rc * 1024);
    float* rel = (float*)carve(Rc * 8);
    char* R2 = carve(Rc * 2048);
    u16* X = (u16*)R1;                   // [Rc][256] f16 (dead after L0)
    u16* H = (u16*)(R1 + Rc * 512);      // [Rc/4][1024] f16 (dead after L0)
    u16* A1 = (u16*)R1;                  // [Rc][512]  (overwrites X+H in L1)
    u16* Qhr = (u16*)R2;                 // [Rc/4][128] (dead before A0 write)
    u16* A0 = (u16*)R2;                  // [Rc][1024] (dead after L1)
    u16* A2 = (u16*)R2;                  // [Rc][256]  (overwrites A0 in L2)

    transpose_chw_hwc<<<dim3(2048, 4, 4), dim3(32, 8), 0, stream>>>(hr, hrT, 65536);
    transpose_chw_hwc<<<dim3(128, 4, 4), dim3(32, 8), 0, stream>>>(feat, featT, 4096);
    transpose_chw_hwc<<<dim3(128, 4, 4), dim3(32, 8), 0, stream>>>(lr, lrT, 4096);
    prep_w0<<<1024, 256, 0, stream>>>(W0, Wt0m, Wthr);
    prep_wt<<<(512 * 1024 + 255) / 256, 256, 0, stream>>>(W1, Wt1, 1024, 512, 1);
    prep_wt<<<(256 * 512 + 255) / 256, 256, 0, stream>>>(W2, Wt2, 512, 256, 1);
    prep_wt<<<(128 * 256 + 255) / 256, 256, 0, stream>>>(W3, Wt3, 256, 128, 1);

    const int mt1 = (int)(Rc / 128);   // 128-row tiles
    const int mt2 = (int)(Rc / 256);   // 256-row tiles (8-phase kernel)
    const int mth = (int)(Rc / 512);   // point rows / 128
    const bool use256 = (Rc % 2048ull) == 0;
    for (int ci = 0; ci < c; ++ci) {
        const int p0 = ci * Pc;
        gather_build<<<Pc / 4, 256, 0, stream>>>(coord, hrT, featT, lrT, X, Qhr,
                                                 rel, p0);
        // h = qhr @ (W0b+W0c) + b0, per point (no relu)
        gemm_f16<<<mth * 8, 256, 0, stream>>>(Qhr, Wthr, b0, H, 128, 1024, 3,
                                              nullptr, nullptr, nullptr, 0);
        // L0 main: [qf|qlr] @ [W0a;-W0c] + h + rel rank-2, relu
        gemm_f16<<<mt1 * 8, 256, 0, stream>>>(X, Wt0m, nullptr, A0, 256, 1024,
                                              3, rel, W0 + 384 * 1024, H, 1);
        if (use256) {
            gemm_f16_256<<<mt2 * 2, 512, 0, stream>>>(A0, Wt1, b1, A1, 1024, 512,
                                                      1, nullptr, nullptr);
            gemm_f16_256<<<mt2 * 1, 512, 0, stream>>>(A1, Wt2, b2, A2, 512, 256,
                                                      0, nullptr, nullptr);
        } else {
            gemm_f16<<<mt1 * 4, 256, 0, stream>>>(A0, Wt1, b1, A1, 1024, 512, 2,
                                                  nullptr, nullptr, nullptr, 1);
            gemm_f16<<<mt1 * 2, 256, 0, stream>>>(A1, Wt2, b2, A2, 512, 256, 1,
                                                  nullptr, nullptr, nullptr, 1);
        }
        // fused L3 + L4 + softmax combine (writes out directly)
        gemm_l3l4<<<mt1, 256, 0, stream>>>(A2, Wt3, b3, W4, b4, out, p0);
    }
}